// Round 6
// baseline (529.043 us; speedup 1.0000x reference)
//
#include <hip/hip_runtime.h>
#include <math.h>

#define N_NODES 50000
#define E_REAL  200000
#define E_MEAN  250000   // real + self-loops (self handled densely in init now)
#define NREL    65
#define HDIM    256
#define NGRAPH  1600
#define NB_R    ((E_REAL + 255) / 256)   // 782 blocks over REAL edges
#define NB_CNT  ((E_MEAN + 255) / 256)   // 977 blocks to also count self-loops
#define TOT_HIST (NREL * NB_R)           // 50830
#define MB      64                        // rows per MFMA block
#define MAX_PB  3264                      // >= 65 + E_REAL/64 = 3190

typedef __attribute__((ext_vector_type(8))) short short8;   // 8 bf16 (4 VGPRs)
typedef __attribute__((ext_vector_type(4))) float floatx4;  // MFMA C/D frag
typedef const __attribute__((address_space(1))) void GPtr;
typedef __attribute__((address_space(3))) void LPtr;

__device__ __forceinline__ unsigned short f2bf(float f) {
    unsigned int u = __float_as_uint(f);
    unsigned int r = u + 0x7FFFu + ((u >> 16) & 1u);  // RNE
    return (unsigned short)(r >> 16);
}
__device__ __forceinline__ float bf2f(unsigned short u) {
    return __uint_as_float(((unsigned int)u) << 16);
}

// async global->LDS, 16B per lane; LDS dest must be wave-uniform base + lane*16
__device__ __forceinline__ void gl_lds16(const unsigned short* g, unsigned short* l) {
    __builtin_amdgcn_global_load_lds((GPtr*)g,
        (LPtr*)(unsigned int)(unsigned long long)(void*)l, 16, 0, 0);
}

// counts: cnt[d][r] over ALL edges (incl self, rel 0); blockHist/cntD over REAL only
__global__ void count_kernel(const int* __restrict__ src, const int* __restrict__ dst,
                             const int* __restrict__ et, int* __restrict__ cnt,
                             int* __restrict__ blockHist, int* __restrict__ cntD) {
    __shared__ int lhist[NREL];
    int t = threadIdx.x;
    if (t < NREL) lhist[t] = 0;
    __syncthreads();
    int e = blockIdx.x * 256 + t;
    if (e < E_REAL) {
        int d = dst[e], r = et[e];
        atomicAdd(&cnt[d * NREL + r], 1);
        atomicAdd(&cntD[d], 1);
        atomicAdd(&lhist[r], 1);
    } else if (e < E_MEAN) {
        atomicAdd(&cnt[(e - E_REAL) * NREL], 1);   // self-loop, rel 0
    }
    __syncthreads();
    if (t < NREL && blockIdx.x < NB_R) blockHist[t * NB_R + blockIdx.x] = lhist[t];
}

// hierarchical exclusive scan, phase 1: per-block partial sums (coalesced)
__global__ void scan_part(const int* __restrict__ in, int* __restrict__ psum, int n) {
    __shared__ int red[1024];
    int t = threadIdx.x;
    int g = blockIdx.x * 1024 + t;
    red[t] = (g < n) ? in[g] : 0;
    __syncthreads();
    for (int off = 512; off >= 1; off >>= 1) {
        if (t < off) red[t] += red[t + off];
        __syncthreads();
    }
    if (t == 0) psum[blockIdx.x] = red[0];
}

// phase 2: block offset + block-local Hillis-Steele exclusive scan
__global__ void scan_apply(const int* __restrict__ in, const int* __restrict__ psum,
                           int* __restrict__ out, int* __restrict__ out2, int n) {
    __shared__ int sums[1024];
    __shared__ int soff;
    int t = threadIdx.x;
    int b = blockIdx.x;
    int g = b * 1024 + t;
    if (t < 64) {
        int v = (t < b) ? psum[t] : 0;
        for (int off = 32; off >= 1; off >>= 1) v += __shfl_down(v, off, 64);
        if (t == 0) soff = v;
    }
    int v = (g < n) ? in[g] : 0;
    sums[t] = v;
    __syncthreads();
    for (int off = 1; off < 1024; off <<= 1) {
        int u = (t >= off) ? sums[t - off] : 0;
        __syncthreads();
        sums[t] += u;
        __syncthreads();
    }
    if (g < n) {
        int excl = soff + sums[t] - v;
        out[g] = excl;
        if (out2) out2[g] = excl;
    }
}

// relation segment metadata from the scanned blockHist
__global__ void meta_kernel(const int* __restrict__ baseArr,
                            int* __restrict__ relStart, int* __restrict__ relTot,
                            int* __restrict__ pBlockStart, int* __restrict__ relOfBlock,
                            int* __restrict__ npb) {
    __shared__ int sStart[NREL + 1];
    __shared__ int sPB[NREL + 1];
    int t = threadIdx.x;
    if (t < NREL) sStart[t] = baseArr[t * NB_R];
    if (t == 0) sStart[NREL] = E_REAL;
    __syncthreads();
    if (t < NREL) {
        relStart[t] = sStart[t];
        relTot[t] = sStart[t + 1] - sStart[t];
    }
    if (t == 0) {
        int a2 = 0;
        for (int r = 0; r < NREL; ++r) {
            sPB[r] = a2;
            int tot = sStart[r + 1] - sStart[r];
            a2 += (tot + MB - 1) / MB;
        }
        sPB[NREL] = a2;
        npb[0] = a2;
    }
    __syncthreads();
    if (t < NREL) pBlockStart[t] = sPB[t];
    int NPB = sPB[NREL];
    for (int b = t; b < NPB; b += 1024) {
        int lo = 0, hi = NREL - 1;
        while (lo < hi) { int mid = (lo + hi + 1) >> 1; if (sPB[mid] <= b) lo = mid; else hi = mid - 1; }
        relOfBlock[b] = lo;
    }
}

// counting-sort scatter by relation (REAL edges); also dst-sorted slot -> pos
__global__ void scatter_sorted(const int* __restrict__ src, const int* __restrict__ dst,
                               const int* __restrict__ et, const int* __restrict__ base,
                               int* __restrict__ perm, int* __restrict__ cursorD,
                               int* __restrict__ pofq) {
    __shared__ int lhist[NREL];
    int t = threadIdx.x;
    int b = blockIdx.x;
    if (t < NREL) lhist[t] = 0;
    __syncthreads();
    int e = b * 256 + t;
    if (e < E_REAL) {
        int d = dst[e], r = et[e];
        int local = atomicAdd(&lhist[r], 1);
        int p = base[r * NB_R + b] + local;
        perm[p] = e;
        int q = atomicAdd(&cursorD[d], 1);
        pofq[q] = p;
    }
}

// fp32 row-major -> bf16 row-major, optional relu
__global__ void cvt_rows(const float* __restrict__ in, unsigned short* __restrict__ out,
                         int nchunk, int relu) {
    int i = blockIdx.x * 256 + threadIdx.x;
    if (i >= nchunk) return;
    const float4* p = (const float4*)in + (size_t)i * 2;
    float4 a = p[0], b = p[1];
    float v[8] = {a.x, a.y, a.z, a.w, b.x, b.y, b.z, b.w};
    short8 o;
#pragma unroll
    for (int j = 0; j < 8; ++j) {
        float f = relu ? fmaxf(v[j], 0.f) : v[j];
        o[j] = (short)f2bf(f);
    }
    ((short8*)out)[i] = o;
}

// W fp32 [R][K][N] -> bf16 [R][N][K]
__global__ void cvt_wT(const float* __restrict__ W, unsigned short* __restrict__ out,
                       int R, int K, int N) {
    int kc8 = K / 8;
    int total = R * N * kc8;
    int i = blockIdx.x * 256 + threadIdx.x;
    if (i >= total) return;
    int kc = i % kc8;
    int tmp = i / kc8;
    int n = tmp % N;
    int r = tmp / N;
    const float* src = W + ((size_t)r * K + kc * 8) * N + n;
    short8 o;
#pragma unroll
    for (int j = 0; j < 8; ++j) o[j] = (short)f2bf(src[(size_t)j * N]);
    ((short8*)out)[i] = o;
}

// one K-sweep: acc += A(lds) @ B(global), 2-deep B prefetch, static 3-slot ring
template<int K>
__device__ __forceinline__ void gemm_pass(const unsigned short* __restrict__ Bp,
                                          const unsigned short* lds,
                                          int lrow, int lk, floatx4 (&acc)[4][4]) {
    constexpr int KS = K / 32;
    short8 bb[3][4];
#pragma unroll
    for (int nf = 0; nf < 4; ++nf)
        bb[0][nf] = *(const short8*)(Bp + (size_t)(nf * 16 + lrow) * K + lk * 8);
#pragma unroll
    for (int nf = 0; nf < 4; ++nf)
        bb[1][nf] = *(const short8*)(Bp + (size_t)(nf * 16 + lrow) * K + 32 + lk * 8);
#pragma unroll
    for (int ks = 0; ks < KS; ++ks) {
        short8 a[4];
#pragma unroll
        for (int mf = 0; mf < 4; ++mf) {
            int row = mf * 16 + lrow;
            int c = (ks * 4 + lk) ^ (row & 7);
            a[mf] = *(const short8*)((const char*)lds + row * (K * 2) + c * 16);
        }
        if (ks + 2 < KS) {
#pragma unroll
            for (int nf = 0; nf < 4; ++nf)
                bb[(ks + 2) % 3][nf] = *(const short8*)(Bp + (size_t)(nf * 16 + lrow) * K + (ks + 2) * 32 + lk * 8);
        }
#pragma unroll
        for (int mf = 0; mf < 4; ++mf)
#pragma unroll
            for (int nf = 0; nf < 4; ++nf)
                acc[mf][nf] = __builtin_amdgcn_mfma_f32_16x16x32_bf16(a[mf], bb[ks % 3][nf], acc[mf][nf], 0, 0, 0);
    }
}

// async A-staging: linear LDS dest, inverse-swizzled global source (chunk sl holds
// global chunk sl^(row&7), so the swizzled MFMA read sees the right data)
template<int K, bool EDGE>
__device__ __forceinline__ void stage_A(const unsigned short* __restrict__ A,
                                        unsigned short* lds, const int* ssrc,
                                        int rowbase, int t) {
    constexpr int CH = K / 8;
#pragma unroll
    for (int i = 0; i < (MB * CH) / 256; ++i) {
        int q = i * 256 + t;
        int row = q / CH, sl = q % CH;
        int srow;
        if constexpr (EDGE) srow = ssrc[row];
        else { srow = rowbase + row; if (srow >= N_NODES) srow = N_NODES - 1; }
        int cg = sl ^ (row & 7);
        gl_lds16(A + (size_t)srow * K + cg * 8, lds + q * 8);
    }
}

// MFMA GEMM: 64 rows x 256 cols per block, 4 waves.
// MODE 0: INIT dense -> fp32 out = A@root + b + (A@Bself)*sw   (fallback)
// MODE 1: EDGE gathered -> weighted fp32 atomic scatter         (fallback)
// MODE 2: INIT dense -> bf16 out (same formula as MODE 0)
// MODE 3: EDGE gathered -> weighted bf16 msg rows
template<int K, int MODE>
__global__ __launch_bounds__(256) void mfma_gemm(
    const unsigned short* __restrict__ A,     // [*][K] bf16 rows
    const unsigned short* __restrict__ B,     // INIT: root panel; EDGE: [R][256][K]
    const unsigned short* __restrict__ Bself, // INIT: W[0] panel; EDGE: unused
    const float* __restrict__ bias,
    float* __restrict__ outF,
    unsigned short* __restrict__ outB,
    const int* __restrict__ perm, const int* __restrict__ srcA,
    const int* __restrict__ dstA, const int* __restrict__ etA,
    const int* __restrict__ cnt,
    const int* __restrict__ relOfBlock, const int* __restrict__ pBlockStart,
    const int* __restrict__ relStart, const int* __restrict__ relTot,
    const int* __restrict__ npb)
{
    constexpr bool EDGE = (MODE == 1 || MODE == 3);
    __shared__ __align__(16) unsigned short lds[MB * HDIM];  // A staging / repack
    __shared__ int ssrc[MB];
    __shared__ int sdst[MB];
    __shared__ float sw[MB];
    int t = threadIdx.x;
    int b = blockIdx.x;
    int rel = 0, rowbase = 0, jb = 0, rs = 0, nval = MB;
    if constexpr (EDGE) {
        if (b >= npb[0]) return;
        rel = relOfBlock[b];
        jb = b - pBlockStart[rel];
        rs = relStart[rel];
        nval = relTot[rel] - jb * MB; if (nval > MB) nval = MB;
        if (t < MB) {
            int s = 0, d = 0; float w = 0.f;
            if (t < nval) {
                int e = perm[rs + jb * MB + t];
                s = srcA[e]; d = dstA[e];
                w = 1.0f / (float)cnt[d * NREL + rel];
            }
            ssrc[t] = s; sdst[t] = d; sw[t] = w;
        }
        __syncthreads();
    } else {
        rowbase = b * MB;
        if (t < MB) {
            int srow = rowbase + t; if (srow >= N_NODES) srow = N_NODES - 1;
            sw[t] = 1.0f / (float)cnt[srow * NREL];   // 1/cnt[d,0] for self term
        }
    }
    stage_A<K, EDGE>(A, lds, ssrc, rowbase, t);
    __syncthreads();   // drains global_load_lds

    int wave = t >> 6, lane = t & 63;
    int n0 = wave * 64;
    int lrow = lane & 15;
    int lk = lane >> 4;
    floatx4 acc[4][4];
#pragma unroll
    for (int mf = 0; mf < 4; ++mf)
#pragma unroll
        for (int nf = 0; nf < 4; ++nf) acc[mf][nf] = (floatx4)0.f;

    if constexpr (EDGE) {
        gemm_pass<K>(B + ((size_t)rel * HDIM + n0) * K, lds, lrow, lk, acc);
    } else {
        // pass 1: self W0 -> acc; scale per-row by 1/cnt; pass 2: root into same acc
        gemm_pass<K>(Bself + (size_t)n0 * K, lds, lrow, lk, acc);
#pragma unroll
        for (int mf = 0; mf < 4; ++mf) {
            int mbase = mf * 16 + lk * 4;
#pragma unroll
            for (int i = 0; i < 4; ++i) {
                float w = sw[mbase + i];
#pragma unroll
                for (int nf = 0; nf < 4; ++nf) acc[mf][nf][i] *= w;
            }
        }
        gemm_pass<K>(B + (size_t)n0 * K, lds, lrow, lk, acc);
    }

    // C/D layout: col = lane&15, row = (lane>>4)*4 + reg
    if constexpr (MODE == 1) {
#pragma unroll
        for (int mf = 0; mf < 4; ++mf) {
            int mbase = mf * 16 + lk * 4;
#pragma unroll
            for (int i = 0; i < 4; ++i) {
                int mm = mbase + i;
                float w = sw[mm];
                if (w != 0.f) {
                    int drow = sdst[mm];
#pragma unroll
                    for (int nf = 0; nf < 4; ++nf) {
                        int col = n0 + nf * 16 + lrow;
                        atomicAdd(&outF[(size_t)drow * HDIM + col], acc[mf][nf][i] * w);
                    }
                }
            }
        }
    } else if constexpr (MODE == 0) {
        float bv[4];
#pragma unroll
        for (int nf = 0; nf < 4; ++nf) bv[nf] = bias[n0 + nf * 16 + lrow];
#pragma unroll
        for (int mf = 0; mf < 4; ++mf) {
            int mbase = mf * 16 + lk * 4;
#pragma unroll
            for (int i = 0; i < 4; ++i) {
                int mm = rowbase + mbase + i;
                if (mm < N_NODES) {
#pragma unroll
                    for (int nf = 0; nf < 4; ++nf) {
                        int col = n0 + nf * 16 + lrow;
                        outF[(size_t)mm * HDIM + col] = acc[mf][nf][i] + bv[nf];
                    }
                }
            }
        }
    } else {
        // MODE 2 / 3: repack to bf16 in LDS, then coalesced row stores
        float bv[4];
        if constexpr (MODE == 2) {
#pragma unroll
            for (int nf = 0; nf < 4; ++nf) bv[nf] = bias[n0 + nf * 16 + lrow];
        }
        __syncthreads();  // A reads done; reuse lds
#pragma unroll
        for (int mf = 0; mf < 4; ++mf) {
            int mbase = mf * 16 + lk * 4;
#pragma unroll
            for (int i = 0; i < 4; ++i) {
                int row = mbase + i;
                float w = (MODE == 3) ? sw[row] : 0.f;
#pragma unroll
                for (int nf = 0; nf < 4; ++nf) {
                    int col = n0 + nf * 16 + lrow;
                    float v = acc[mf][nf][i];
                    if constexpr (MODE == 3) v *= w;
                    else v += bv[nf];
                    lds[row * HDIM + col] = f2bf(v);
                }
            }
        }
        __syncthreads();
        int limit;
        size_t rb;
        if constexpr (MODE == 3) { limit = nval; rb = (size_t)rs + (size_t)jb * MB; }
        else { limit = N_NODES - rowbase; if (limit > MB) limit = MB; rb = (size_t)rowbase; }
        for (int q = t; q < limit * 32; q += 256) {
            int row = q >> 5, c = q & 31;
            *(uint4*)(outB + (rb + row) * HDIM + c * 8) = *(const uint4*)(lds + row * HDIM + c * 8);
        }
    }
}

// gather-reduce per dst, wave-per-dst, ushort4 (8B/lane) vectorized.
// FUSE_POOL=0: hout = relu(hinit+sum) bf16. FUSE_POOL=1: pool -> emb atomics.
template<int FUSE_POOL>
__global__ __launch_bounds__(256) void reduce_kernel(
    const unsigned short* __restrict__ hinit, const unsigned short* __restrict__ msg,
    const int* __restrict__ pofq, const int* __restrict__ startD,
    const int* __restrict__ cntD, unsigned short* __restrict__ hout,
    const int* __restrict__ batch, const float* __restrict__ wsw,
    const float* __restrict__ wsb, float* __restrict__ emb)
{
    int t = threadIdx.x;
    int lane = t & 63;
    int d = blockIdx.x * 4 + (t >> 6);
    if (d >= N_NODES) return;
    int s0 = startD[d], n = cntD[d];
    ushort4 hv = *(const ushort4*)(hinit + (size_t)d * HDIM + lane * 4);
    float v0 = bf2f(hv.x), v1 = bf2f(hv.y), v2 = bf2f(hv.z), v3 = bf2f(hv.w);
    for (int q = 0; q < n; ++q) {
        int p = pofq[s0 + q];
        ushort4 m = *(const ushort4*)(msg + (size_t)p * HDIM + lane * 4);
        v0 += bf2f(m.x); v1 += bf2f(m.y); v2 += bf2f(m.z); v3 += bf2f(m.w);
    }
    v0 = fmaxf(v0, 0.f); v1 = fmaxf(v1, 0.f); v2 = fmaxf(v2, 0.f); v3 = fmaxf(v3, 0.f);
    if constexpr (FUSE_POOL == 0) {
        ushort4 o;
        o.x = f2bf(v0); o.y = f2bf(v1); o.z = f2bf(v2); o.w = f2bf(v3);
        *(ushort4*)(hout + (size_t)d * HDIM + lane * 4) = o;
    } else {
        float4 wv = *(const float4*)(wsw + lane * 4);
        float pp = v0 * wv.x + v1 * wv.y + v2 * wv.z + v3 * wv.w;
        for (int off2 = 32; off2 >= 1; off2 >>= 1) pp += __shfl_down(pp, off2, 64);
        float tot = __shfl(pp, 0, 64);
        float sig = 1.0f / (1.0f + expf(-(tot + wsb[0])));
        float* ep = emb + (size_t)batch[d] * HDIM + lane * 4;
        atomicAdd(ep + 0, sig * v0);
        atomicAdd(ep + 1, sig * v1);
        atomicAdd(ep + 2, sig * v2);
        atomicAdd(ep + 3, sig * v3);
    }
}

// fallback pool (fp32 h input)
__global__ void pool_kernel(const float* __restrict__ h, const int* __restrict__ batch,
                            const float* __restrict__ wsw, const float* __restrict__ wsb,
                            float* __restrict__ emb) {
    int i = blockIdx.x;
    int t = threadIdx.x;
    float v = fmaxf(h[(size_t)i * HDIM + t], 0.f);
    float p = v * wsw[t];
    for (int off = 32; off >= 1; off >>= 1) p += __shfl_down(p, off, 64);
    __shared__ float red[4];
    __shared__ float ssig;
    if ((t & 63) == 0) red[t >> 6] = p;
    __syncthreads();
    if (t == 0) {
        float s = red[0] + red[1] + red[2] + red[3] + wsb[0];
        ssig = 1.0f / (1.0f + expf(-s));
    }
    __syncthreads();
    atomicAdd(&emb[(size_t)batch[i] * HDIM + t], ssig * v);
}

__global__ void mlp_kernel(const float* __restrict__ emb,
                           const float* __restrict__ m1w, const float* __restrict__ m1b,
                           const float* __restrict__ m2w, const float* __restrict__ m2b,
                           const float* __restrict__ m3w, const float* __restrict__ m3b,
                           const float* __restrict__ ow,  const float* __restrict__ ob,
                           float* __restrict__ out) {
    int g = blockIdx.x;
    int t = threadIdx.x; // 64 threads = 1 wave
    __shared__ float e[HDIM];
    __shared__ float z1[64], z2[64];
    for (int idx = t; idx < HDIM; idx += 64) e[idx] = emb[(size_t)g * HDIM + idx];
    __syncthreads();
    float a = m1b[t];
    for (int k = 0; k < HDIM; ++k) a += e[k] * m1w[k * 64 + t];
    z1[t] = fmaxf(a, 0.f);
    __syncthreads();
    a = m2b[t];
    for (int k = 0; k < 64; ++k) a += z1[k] * m2w[k * 64 + t];
    z2[t] = fmaxf(a, 0.f);
    __syncthreads();
    a = m3b[t];
    for (int k = 0; k < 64; ++k) a += z2[k] * m3w[k * 64 + t];
    float p = a * ow[t];
    for (int off = 32; off >= 1; off >>= 1) p += __shfl_down(p, off, 64);
    if (t == 0) out[g] = p + ob[0];
}

extern "C" void kernel_launch(void* const* d_in, const int* in_sizes, int n_in,
                              void* d_out, int out_size, void* d_ws, size_t ws_size,
                              hipStream_t stream) {
    const float* x     = (const float*)d_in[0];
    const int*   ei    = (const int*)d_in[1];
    const int*   src   = ei;
    const int*   dst   = ei + E_REAL;
    const int*   et    = (const int*)d_in[2];
    const int*   batch = (const int*)d_in[3];
    const float* W1    = (const float*)d_in[4];
    const float* root1 = (const float*)d_in[5];
    const float* b1    = (const float*)d_in[6];
    const float* W2    = (const float*)d_in[7];
    const float* root2 = (const float*)d_in[8];
    const float* b2    = (const float*)d_in[9];
    const float* wsw   = (const float*)d_in[10];
    const float* wsb   = (const float*)d_in[11];
    const float* m1w   = (const float*)d_in[12];
    const float* m1b   = (const float*)d_in[13];
    const float* m2w   = (const float*)d_in[14];
    const float* m2b   = (const float*)d_in[15];
    const float* m3w   = (const float*)d_in[16];
    const float* m3b   = (const float*)d_in[17];
    const float* ow    = (const float*)d_in[18];
    const float* ob    = (const float*)d_in[19];

    char* ws = (char*)d_ws;
    size_t off = 0;
    auto alloc = [&](size_t bytes) {
        void* p = ws + off;
        off = (off + bytes + 255) & ~(size_t)255;
        return p;
    };
    // common buffers
    int*   cnt       = (int*)alloc((size_t)N_NODES * NREL * 4);     // 13.0 MB
    int*   blockHist = (int*)alloc((size_t)TOT_HIST * 4);
    int*   baseArr   = (int*)alloc((size_t)TOT_HIST * 4);
    int*   perm      = (int*)alloc((size_t)E_REAL * 4);             // 0.8 MB
    int*   relStartA = (int*)alloc(NREL * 4);
    int*   relTotA   = (int*)alloc(NREL * 4);
    int*   pbStartA  = (int*)alloc(NREL * 4);
    int*   relOfBlk  = (int*)alloc(MAX_PB * 4);
    int*   npb       = (int*)alloc(4);
    int*   psumA     = (int*)alloc(64 * 4);
    int*   psumB     = (int*)alloc(64 * 4);
    unsigned short* xb  = (unsigned short*)alloc((size_t)N_NODES * 128 * 2);    // 12.8 MB
    unsigned short* w1b = (unsigned short*)alloc((size_t)NREL * 256 * 128 * 2); // 4.3 MB
    unsigned short* w2b = (unsigned short*)alloc((size_t)NREL * 256 * 256 * 2); // 8.5 MB
    unsigned short* r1b = (unsigned short*)alloc((size_t)256 * 128 * 2);
    unsigned short* r2b = (unsigned short*)alloc((size_t)256 * 256 * 2);
    unsigned short* h1b = (unsigned short*)alloc((size_t)N_NODES * HDIM * 2);   // 25.6 MB
    float* emb = (float*)alloc((size_t)NGRAPH * HDIM * 4);                       // 1.6 MB
    size_t off_common = off;

    // fast-path extras
    unsigned short* hinit = (unsigned short*)alloc((size_t)N_NODES * HDIM * 2); // 25.6 MB
    unsigned short* msg   = (unsigned short*)alloc((size_t)E_REAL * HDIM * 2);  // 102.4 MB
    int* pofq    = (int*)alloc((size_t)E_REAL * 4);
    int* cntD    = (int*)alloc((size_t)N_NODES * 4);
    int* startD  = (int*)alloc((size_t)N_NODES * 4);
    int* cursorD = (int*)alloc((size_t)N_NODES * 4);
    size_t need_fast = off;

    float* hf = nullptr;
    bool fast = (ws_size >= need_fast);
    if (!fast) {
        off = off_common;
        hf = (float*)alloc((size_t)N_NODES * HDIM * 4);  // 51.2 MB
        char* hh = (char*)hf;   // dst structures alias hf (used before hf written)
        pofq    = (int*)hh;                                 hh += (size_t)E_REAL * 4;
        cntD    = (int*)hh;                                 hh += (size_t)N_NODES * 4;
        startD  = (int*)hh;                                 hh += (size_t)N_NODES * 4;
        cursorD = (int*)hh;
        hinit = h1b;  // unused sink
        msg = h1b;    // unused sink
    }

    hipMemsetAsync(cnt, 0, (size_t)N_NODES * NREL * 4, stream);
    hipMemsetAsync(cntD, 0, (size_t)N_NODES * 4, stream);
    hipMemsetAsync(emb, 0, (size_t)NGRAPH * HDIM * 4, stream);

    count_kernel<<<NB_CNT, 256, 0, stream>>>(src, dst, et, cnt, blockHist, cntD);
    scan_part<<<64, 1024, 0, stream>>>(blockHist, psumA, TOT_HIST);
    scan_apply<<<64, 1024, 0, stream>>>(blockHist, psumA, baseArr, nullptr, TOT_HIST);
    meta_kernel<<<1, 1024, 0, stream>>>(baseArr, relStartA, relTotA, pbStartA, relOfBlk, npb);
    scan_part<<<64, 1024, 0, stream>>>(cntD, psumB, N_NODES);
    scan_apply<<<64, 1024, 0, stream>>>(cntD, psumB, startD, cursorD, N_NODES);
    scatter_sorted<<<NB_R, 256, 0, stream>>>(src, dst, et, baseArr, perm, cursorD, pofq);

    cvt_rows<<<(N_NODES * 128 / 8 + 255) / 256, 256, 0, stream>>>(x, xb, N_NODES * 128 / 8, 0);
    cvt_wT<<<(NREL * 256 * 16 + 255) / 256, 256, 0, stream>>>(W1, w1b, NREL, 128, 256);
    cvt_wT<<<(NREL * 256 * 32 + 255) / 256, 256, 0, stream>>>(W2, w2b, NREL, 256, 256);
    cvt_wT<<<(256 * 16 + 255) / 256, 256, 0, stream>>>(root1, r1b, 1, 128, 256);
    cvt_wT<<<(256 * 32 + 255) / 256, 256, 0, stream>>>(root2, r2b, 1, 256, 256);

    const int grid_init = (N_NODES + MB - 1) / MB;  // 782

    if (fast) {
        // layer 1
        mfma_gemm<128, 2><<<grid_init, 256, 0, stream>>>(xb, r1b, w1b, b1, nullptr, hinit,
            nullptr, nullptr, nullptr, nullptr, cnt, nullptr, nullptr, nullptr, nullptr, nullptr);
        mfma_gemm<128, 3><<<MAX_PB, 256, 0, stream>>>(xb, w1b, nullptr, nullptr, nullptr, msg,
            perm, src, dst, et, cnt, relOfBlk, pbStartA, relStartA, relTotA, npb);
        reduce_kernel<0><<<N_NODES / 4, 256, 0, stream>>>(hinit, msg, pofq, startD, cntD,
            h1b, nullptr, nullptr, nullptr, nullptr);
        // layer 2 (pool fused into reduce)
        mfma_gemm<256, 2><<<grid_init, 256, 0, stream>>>(h1b, r2b, w2b, b2, nullptr, hinit,
            nullptr, nullptr, nullptr, nullptr, cnt, nullptr, nullptr, nullptr, nullptr, nullptr);
        mfma_gemm<256, 3><<<MAX_PB, 256, 0, stream>>>(h1b, w2b, nullptr, nullptr, nullptr, msg,
            perm, src, dst, et, cnt, relOfBlk, pbStartA, relStartA, relTotA, npb);
        reduce_kernel<1><<<N_NODES / 4, 256, 0, stream>>>(hinit, msg, pofq, startD, cntD,
            nullptr, batch, wsw, wsb, emb);
    } else {
        mfma_gemm<128, 0><<<grid_init, 256, 0, stream>>>(xb, r1b, w1b, b1, hf, nullptr,
            nullptr, nullptr, nullptr, nullptr, cnt, nullptr, nullptr, nullptr, nullptr, nullptr);
        mfma_gemm<128, 1><<<MAX_PB, 256, 0, stream>>>(xb, w1b, nullptr, nullptr, hf, nullptr,
            perm, src, dst, et, cnt, relOfBlk, pbStartA, relStartA, relTotA, npb);
        cvt_rows<<<(N_NODES * HDIM / 8 + 255) / 256, 256, 0, stream>>>(hf, h1b, N_NODES * HDIM / 8, 1);
        mfma_gemm<256, 0><<<grid_init, 256, 0, stream>>>(h1b, r2b, w2b, b2, hf, nullptr,
            nullptr, nullptr, nullptr, nullptr, cnt, nullptr, nullptr, nullptr, nullptr, nullptr);
        mfma_gemm<256, 1><<<MAX_PB, 256, 0, stream>>>(h1b, w2b, nullptr, nullptr, hf, nullptr,
            perm, src, dst, et, cnt, relOfBlk, pbStartA, relStartA, relTotA, npb);
        pool_kernel<<<N_NODES, 256, 0, stream>>>(hf, batch, wsw, wsb, emb);
    }
    mlp_kernel<<<NGRAPH, 64, 0, stream>>>(emb, m1w, m1b, m2w, m2b, m3w, m3b, ow, ob, (float*)d_out);
}

// Round 7
// 378.175 us; speedup vs baseline: 1.3989x; 1.3989x over previous
//
#include <hip/hip_runtime.h>
#include <math.h>

#define N_NODES 50000
#define E_REAL  200000
#define E_MEAN  250000   // real + self-loops (self handled densely in init)
#define NREL    65
#define HDIM    256
#define NGRAPH  1600
#define NB_R    ((E_REAL + 255) / 256)   // 782 blocks over REAL edges
#define NB_CNT  ((E_MEAN + 255) / 256)   // 977 blocks to also count self-loops
#define TOT_HIST (NREL * NB_R)           // 50830
#define MB      64                        // rows per MFMA block
#define MAX_PB  3264                      // >= 65 + E_REAL/64 = 3190

typedef __attribute__((ext_vector_type(8))) short short8;   // 8 bf16 (4 VGPRs)
typedef __attribute__((ext_vector_type(4))) float floatx4;  // MFMA C/D frag
typedef const __attribute__((address_space(1))) void GPtr;
typedef __attribute__((address_space(3))) void LPtr;

__device__ __forceinline__ unsigned short f2bf(float f) {
    unsigned int u = __float_as_uint(f);
    unsigned int r = u + 0x7FFFu + ((u >> 16) & 1u);  // RNE
    return (unsigned short)(r >> 16);
}
__device__ __forceinline__ float bf2f(unsigned short u) {
    return __uint_as_float(((unsigned int)u) << 16);
}

// async global->LDS, 16B per lane; LDS dest must be wave-uniform base + lane*16
__device__ __forceinline__ void gl_lds16(const unsigned short* g, unsigned short* l) {
    __builtin_amdgcn_global_load_lds((GPtr*)g,
        (LPtr*)(unsigned int)(unsigned long long)(void*)l, 16, 0, 0);
}

// counts: cnt[d][r] over ALL edges (incl self, rel 0); blockHist/cntD over REAL only
__global__ void count_kernel(const int* __restrict__ src, const int* __restrict__ dst,
                             const int* __restrict__ et, int* __restrict__ cnt,
                             int* __restrict__ blockHist, int* __restrict__ cntD) {
    __shared__ int lhist[NREL];
    int t = threadIdx.x;
    if (t < NREL) lhist[t] = 0;
    __syncthreads();
    int e = blockIdx.x * 256 + t;
    if (e < E_REAL) {
        int d = dst[e], r = et[e];
        atomicAdd(&cnt[d * NREL + r], 1);
        atomicAdd(&cntD[d], 1);
        atomicAdd(&lhist[r], 1);
    } else if (e < E_MEAN) {
        atomicAdd(&cnt[(e - E_REAL) * NREL], 1);   // self-loop, rel 0
    }
    __syncthreads();
    if (t < NREL && blockIdx.x < NB_R) blockHist[t * NB_R + blockIdx.x] = lhist[t];
}

// hierarchical exclusive scan, phase 1: per-block partial sums (coalesced)
__global__ void scan_part(const int* __restrict__ in, int* __restrict__ psum, int n) {
    __shared__ int red[1024];
    int t = threadIdx.x;
    int g = blockIdx.x * 1024 + t;
    red[t] = (g < n) ? in[g] : 0;
    __syncthreads();
    for (int off = 512; off >= 1; off >>= 1) {
        if (t < off) red[t] += red[t + off];
        __syncthreads();
    }
    if (t == 0) psum[blockIdx.x] = red[0];
}

// phase 2: block offset + block-local Hillis-Steele exclusive scan
__global__ void scan_apply(const int* __restrict__ in, const int* __restrict__ psum,
                           int* __restrict__ out, int* __restrict__ out2, int n) {
    __shared__ int sums[1024];
    __shared__ int soff;
    int t = threadIdx.x;
    int b = blockIdx.x;
    int g = b * 1024 + t;
    if (t < 64) {
        int v = (t < b) ? psum[t] : 0;
        for (int off = 32; off >= 1; off >>= 1) v += __shfl_down(v, off, 64);
        if (t == 0) soff = v;
    }
    int v = (g < n) ? in[g] : 0;
    sums[t] = v;
    __syncthreads();
    for (int off = 1; off < 1024; off <<= 1) {
        int u = (t >= off) ? sums[t - off] : 0;
        __syncthreads();
        sums[t] += u;
        __syncthreads();
    }
    if (g < n) {
        int excl = soff + sums[t] - v;
        out[g] = excl;
        if (out2) out2[g] = excl;
    }
}

// relation segment metadata from the scanned blockHist
__global__ void meta_kernel(const int* __restrict__ baseArr,
                            int* __restrict__ relStart, int* __restrict__ relTot,
                            int* __restrict__ pBlockStart, int* __restrict__ relOfBlock,
                            int* __restrict__ npb) {
    __shared__ int sStart[NREL + 1];
    __shared__ int sPB[NREL + 1];
    int t = threadIdx.x;
    if (t < NREL) sStart[t] = baseArr[t * NB_R];
    if (t == 0) sStart[NREL] = E_REAL;
    __syncthreads();
    if (t < NREL) {
        relStart[t] = sStart[t];
        relTot[t] = sStart[t + 1] - sStart[t];
    }
    if (t == 0) {
        int a2 = 0;
        for (int r = 0; r < NREL; ++r) {
            sPB[r] = a2;
            int tot = sStart[r + 1] - sStart[r];
            a2 += (tot + MB - 1) / MB;
        }
        sPB[NREL] = a2;
        npb[0] = a2;
    }
    __syncthreads();
    if (t < NREL) pBlockStart[t] = sPB[t];
    int NPB = sPB[NREL];
    for (int b = t; b < NPB; b += 1024) {
        int lo = 0, hi = NREL - 1;
        while (lo < hi) { int mid = (lo + hi + 1) >> 1; if (sPB[mid] <= b) lo = mid; else hi = mid - 1; }
        relOfBlock[b] = lo;
    }
}

// counting-sort scatter by relation (REAL edges); qofp[p] = dst-sorted slot
__global__ void scatter_sorted(const int* __restrict__ src, const int* __restrict__ dst,
                               const int* __restrict__ et, const int* __restrict__ base,
                               int* __restrict__ perm, int* __restrict__ cursorD,
                               int* __restrict__ qofp) {
    __shared__ int lhist[NREL];
    int t = threadIdx.x;
    int b = blockIdx.x;
    if (t < NREL) lhist[t] = 0;
    __syncthreads();
    int e = b * 256 + t;
    if (e < E_REAL) {
        int d = dst[e], r = et[e];
        int local = atomicAdd(&lhist[r], 1);
        int p = base[r * NB_R + b] + local;
        perm[p] = e;
        int q = atomicAdd(&cursorD[d], 1);
        qofp[p] = q;
    }
}

// fp32 row-major -> bf16 row-major, optional relu
__global__ void cvt_rows(const float* __restrict__ in, unsigned short* __restrict__ out,
                         int nchunk, int relu) {
    int i = blockIdx.x * 256 + threadIdx.x;
    if (i >= nchunk) return;
    const float4* p = (const float4*)in + (size_t)i * 2;
    float4 a = p[0], b = p[1];
    float v[8] = {a.x, a.y, a.z, a.w, b.x, b.y, b.z, b.w};
    short8 o;
#pragma unroll
    for (int j = 0; j < 8; ++j) {
        float f = relu ? fmaxf(v[j], 0.f) : v[j];
        o[j] = (short)f2bf(f);
    }
    ((short8*)out)[i] = o;
}

// W fp32 [R][K][N] -> bf16 [R][N][K]
__global__ void cvt_wT(const float* __restrict__ W, unsigned short* __restrict__ out,
                       int R, int K, int N) {
    int kc8 = K / 8;
    int total = R * N * kc8;
    int i = blockIdx.x * 256 + threadIdx.x;
    if (i >= total) return;
    int kc = i % kc8;
    int tmp = i / kc8;
    int n = tmp % N;
    int r = tmp / N;
    const float* src = W + ((size_t)r * K + kc * 8) * N + n;
    short8 o;
#pragma unroll
    for (int j = 0; j < 8; ++j) o[j] = (short)f2bf(src[(size_t)j * N]);
    ((short8*)out)[i] = o;
}

// one K-sweep: acc += A(lds) @ B(global), 2-deep B prefetch, static 3-slot ring
template<int K>
__device__ __forceinline__ void gemm_pass(const unsigned short* __restrict__ Bp,
                                          const unsigned short* lds,
                                          int lrow, int lk, floatx4 (&acc)[4][4]) {
    constexpr int KS = K / 32;
    short8 bb[3][4];
#pragma unroll
    for (int nf = 0; nf < 4; ++nf)
        bb[0][nf] = *(const short8*)(Bp + (size_t)(nf * 16 + lrow) * K + lk * 8);
#pragma unroll
    for (int nf = 0; nf < 4; ++nf)
        bb[1][nf] = *(const short8*)(Bp + (size_t)(nf * 16 + lrow) * K + 32 + lk * 8);
#pragma unroll
    for (int ks = 0; ks < KS; ++ks) {
        short8 a[4];
#pragma unroll
        for (int mf = 0; mf < 4; ++mf) {
            int row = mf * 16 + lrow;
            int c = (ks * 4 + lk) ^ (row & 7);
            a[mf] = *(const short8*)((const char*)lds + row * (K * 2) + c * 16);
        }
        if (ks + 2 < KS) {
#pragma unroll
            for (int nf = 0; nf < 4; ++nf)
                bb[(ks + 2) % 3][nf] = *(const short8*)(Bp + (size_t)(nf * 16 + lrow) * K + (ks + 2) * 32 + lk * 8);
        }
#pragma unroll
        for (int mf = 0; mf < 4; ++mf)
#pragma unroll
            for (int nf = 0; nf < 4; ++nf)
                acc[mf][nf] = __builtin_amdgcn_mfma_f32_16x16x32_bf16(a[mf], bb[ks % 3][nf], acc[mf][nf], 0, 0, 0);
    }
}

// async A-staging: linear LDS dest, inverse-swizzled global source
template<int K, bool EDGE>
__device__ __forceinline__ void stage_A(const unsigned short* __restrict__ A,
                                        unsigned short* lds, const int* ssrc,
                                        int rowbase, int t) {
    constexpr int CH = K / 8;
#pragma unroll
    for (int i = 0; i < (MB * CH) / 256; ++i) {
        int q = i * 256 + t;
        int row = q / CH, sl = q % CH;
        int srow;
        if constexpr (EDGE) srow = ssrc[row];
        else { srow = rowbase + row; if (srow >= N_NODES) srow = N_NODES - 1; }
        int cg = sl ^ (row & 7);
        gl_lds16(A + (size_t)srow * K + cg * 8, lds + q * 8);
    }
}

// MFMA GEMM: 64 rows x 256 cols per block, 4 waves.
// MODE 0: INIT dense -> fp32 out = A@root + b + (A@Bself)*sw   (fallback)
// MODE 1: EDGE gathered -> weighted fp32 atomic scatter         (fallback)
// MODE 2: INIT dense -> bf16 out (same formula as MODE 0)
// MODE 3: EDGE gathered -> weighted bf16 msg rows at DST-SORTED positions
template<int K, int MODE>
__global__ __launch_bounds__(256) void mfma_gemm(
    const unsigned short* __restrict__ A,     // [*][K] bf16 rows
    const unsigned short* __restrict__ B,     // INIT: root panel; EDGE: [R][256][K]
    const unsigned short* __restrict__ Bself, // INIT: W[0] panel; EDGE: unused
    const float* __restrict__ bias,
    float* __restrict__ outF,
    unsigned short* __restrict__ outB,
    const int* __restrict__ perm, const int* __restrict__ srcA,
    const int* __restrict__ dstA, const int* __restrict__ etA,
    const int* __restrict__ cnt,
    const int* __restrict__ relOfBlock, const int* __restrict__ pBlockStart,
    const int* __restrict__ relStart, const int* __restrict__ relTot,
    const int* __restrict__ npb, const int* __restrict__ qofp)
{
    constexpr bool EDGE = (MODE == 1 || MODE == 3);
    __shared__ __align__(16) unsigned short lds[MB * HDIM];  // A staging / repack
    __shared__ int ssrc[MB];
    __shared__ int sdst[MB];
    __shared__ int sqd[MB];
    __shared__ float sw[MB];
    int t = threadIdx.x;
    int b = blockIdx.x;
    int rel = 0, rowbase = 0, jb = 0, rs = 0, nval = MB;
    if constexpr (EDGE) {
        if (b >= npb[0]) return;
        rel = relOfBlock[b];
        jb = b - pBlockStart[rel];
        rs = relStart[rel];
        nval = relTot[rel] - jb * MB; if (nval > MB) nval = MB;
        if (t < MB) {
            int s = 0, d = 0, qd = 0; float w = 0.f;
            if (t < nval) {
                int p = rs + jb * MB + t;
                int e = perm[p];
                s = srcA[e]; d = dstA[e];
                w = 1.0f / (float)cnt[d * NREL + rel];
                if constexpr (MODE == 3) qd = qofp[p];
            }
            ssrc[t] = s; sdst[t] = d; sw[t] = w; sqd[t] = qd;
        }
        __syncthreads();
    } else {
        rowbase = b * MB;
        if (t < MB) {
            int srow = rowbase + t; if (srow >= N_NODES) srow = N_NODES - 1;
            sw[t] = 1.0f / (float)cnt[srow * NREL];   // 1/cnt[d,0] for self term
        }
    }
    stage_A<K, EDGE>(A, lds, ssrc, rowbase, t);
    __syncthreads();   // drains global_load_lds

    int wave = t >> 6, lane = t & 63;
    int n0 = wave * 64;
    int lrow = lane & 15;
    int lk = lane >> 4;
    floatx4 acc[4][4];
#pragma unroll
    for (int mf = 0; mf < 4; ++mf)
#pragma unroll
        for (int nf = 0; nf < 4; ++nf) acc[mf][nf] = (floatx4)0.f;

    if constexpr (EDGE) {
        gemm_pass<K>(B + ((size_t)rel * HDIM + n0) * K, lds, lrow, lk, acc);
    } else {
        gemm_pass<K>(Bself + (size_t)n0 * K, lds, lrow, lk, acc);
#pragma unroll
        for (int mf = 0; mf < 4; ++mf) {
            int mbase = mf * 16 + lk * 4;
#pragma unroll
            for (int i = 0; i < 4; ++i) {
                float w = sw[mbase + i];
#pragma unroll
                for (int nf = 0; nf < 4; ++nf) acc[mf][nf][i] *= w;
            }
        }
        gemm_pass<K>(B + (size_t)n0 * K, lds, lrow, lk, acc);
    }

    // C/D layout: col = lane&15, row = (lane>>4)*4 + reg
    if constexpr (MODE == 1) {
#pragma unroll
        for (int mf = 0; mf < 4; ++mf) {
            int mbase = mf * 16 + lk * 4;
#pragma unroll
            for (int i = 0; i < 4; ++i) {
                int mm = mbase + i;
                float w = sw[mm];
                if (w != 0.f) {
                    int drow = sdst[mm];
#pragma unroll
                    for (int nf = 0; nf < 4; ++nf) {
                        int col = n0 + nf * 16 + lrow;
                        atomicAdd(&outF[(size_t)drow * HDIM + col], acc[mf][nf][i] * w);
                    }
                }
            }
        }
    } else if constexpr (MODE == 0) {
        float bv[4];
#pragma unroll
        for (int nf = 0; nf < 4; ++nf) bv[nf] = bias[n0 + nf * 16 + lrow];
#pragma unroll
        for (int mf = 0; mf < 4; ++mf) {
            int mbase = mf * 16 + lk * 4;
#pragma unroll
            for (int i = 0; i < 4; ++i) {
                int mm = rowbase + mbase + i;
                if (mm < N_NODES) {
#pragma unroll
                    for (int nf = 0; nf < 4; ++nf) {
                        int col = n0 + nf * 16 + lrow;
                        outF[(size_t)mm * HDIM + col] = acc[mf][nf][i] + bv[nf];
                    }
                }
            }
        }
    } else {
        // MODE 2 / 3: repack to bf16 in LDS, then coalesced row stores
        float bv[4];
        if constexpr (MODE == 2) {
#pragma unroll
            for (int nf = 0; nf < 4; ++nf) bv[nf] = bias[n0 + nf * 16 + lrow];
        }
        __syncthreads();  // A reads done; reuse lds
#pragma unroll
        for (int mf = 0; mf < 4; ++mf) {
            int mbase = mf * 16 + lk * 4;
#pragma unroll
            for (int i = 0; i < 4; ++i) {
                int row = mbase + i;
                float w = (MODE == 3) ? sw[row] : 0.f;
#pragma unroll
                for (int nf = 0; nf < 4; ++nf) {
                    int col = n0 + nf * 16 + lrow;
                    float v = acc[mf][nf][i];
                    if constexpr (MODE == 3) v *= w;
                    else v += bv[nf];
                    lds[row * HDIM + col] = f2bf(v);
                }
            }
        }
        __syncthreads();
        if constexpr (MODE == 3) {
            // scattered rows: msg[qofp[p]] (dst-sorted) — row itself 512B contiguous
            for (int q = t; q < nval * 32; q += 256) {
                int row = q >> 5, c = q & 31;
                *(uint4*)(outB + (size_t)sqd[row] * HDIM + c * 8) = *(const uint4*)(lds + row * HDIM + c * 8);
            }
        } else {
            int limit = N_NODES - rowbase; if (limit > MB) limit = MB;
            for (int q = t; q < limit * 32; q += 256) {
                int row = q >> 5, c = q & 31;
                *(uint4*)(outB + ((size_t)rowbase + row) * HDIM + c * 8) = *(const uint4*)(lds + row * HDIM + c * 8);
            }
        }
    }
}

// gather-reduce: msg rows for dst d are CONTIGUOUS [startD[d], +cntD[d]).
// wave-per-dst, ushort4; hout = relu(hinit + sum) bf16. Pure streaming.
__global__ __launch_bounds__(256) void reduce_kernel(
    const unsigned short* __restrict__ hinit, const unsigned short* __restrict__ msg,
    const int* __restrict__ startD, const int* __restrict__ cntD,
    unsigned short* __restrict__ hout)
{
    int t = threadIdx.x;
    int lane = t & 63;
    int d = blockIdx.x * 4 + (t >> 6);
    if (d >= N_NODES) return;
    int s0 = startD[d], n = cntD[d];
    ushort4 hv = *(const ushort4*)(hinit + (size_t)d * HDIM + lane * 4);
    float v0 = bf2f(hv.x), v1 = bf2f(hv.y), v2 = bf2f(hv.z), v3 = bf2f(hv.w);
    const unsigned short* mp = msg + (size_t)s0 * HDIM + lane * 4;
#pragma unroll 4
    for (int q = 0; q < n; ++q) {
        ushort4 m = *(const ushort4*)(mp + (size_t)q * HDIM);
        v0 += bf2f(m.x); v1 += bf2f(m.y); v2 += bf2f(m.z); v3 += bf2f(m.w);
    }
    ushort4 o;
    o.x = f2bf(fmaxf(v0, 0.f)); o.y = f2bf(fmaxf(v1, 0.f));
    o.z = f2bf(fmaxf(v2, 0.f)); o.w = f2bf(fmaxf(v3, 0.f));
    *(ushort4*)(hout + (size_t)d * HDIM + lane * 4) = o;
}

// per-graph pooling, atomic-free: batch is sorted, so graph g's nodes are a
// contiguous range found by binary search. One block per graph, wave-per-node.
__global__ __launch_bounds__(256) void pool_graph(
    const unsigned short* __restrict__ h, const int* __restrict__ batch,
    const float* __restrict__ wsw, const float* __restrict__ wsb,
    float* __restrict__ emb)
{
    int g = blockIdx.x;
    int t = threadIdx.x;
    __shared__ int slo, shi;
    __shared__ float sacc[4][HDIM];
    if (t == 0) {
        int lo = 0, hi = N_NODES;
        while (lo < hi) { int m = (lo + hi) >> 1; if (batch[m] < g) lo = m + 1; else hi = m; }
        slo = lo;
        int lo2 = lo, hi2 = N_NODES;
        while (lo2 < hi2) { int m = (lo2 + hi2) >> 1; if (batch[m] < g + 1) lo2 = m + 1; else hi2 = m; }
        shi = lo2;
    }
    __syncthreads();
    int wave = t >> 6, lane = t & 63;
    float4 wv = *(const float4*)(wsw + lane * 4);
    float wb = wsb[0];
    float a0 = 0.f, a1 = 0.f, a2 = 0.f, a3 = 0.f;
    for (int i = slo + wave; i < shi; i += 4) {
        ushort4 hv = *(const ushort4*)(h + (size_t)i * HDIM + lane * 4);
        float v0 = bf2f(hv.x), v1 = bf2f(hv.y), v2 = bf2f(hv.z), v3 = bf2f(hv.w);
        float pp = v0 * wv.x + v1 * wv.y + v2 * wv.z + v3 * wv.w;
        for (int off = 32; off >= 1; off >>= 1) pp += __shfl_down(pp, off, 64);
        float tot = __shfl(pp, 0, 64);
        float sig = 1.0f / (1.0f + expf(-(tot + wb)));
        a0 += sig * v0; a1 += sig * v1; a2 += sig * v2; a3 += sig * v3;
    }
    sacc[wave][lane * 4 + 0] = a0; sacc[wave][lane * 4 + 1] = a1;
    sacc[wave][lane * 4 + 2] = a2; sacc[wave][lane * 4 + 3] = a3;
    __syncthreads();
    emb[(size_t)g * HDIM + t] = sacc[0][t] + sacc[1][t] + sacc[2][t] + sacc[3][t];
}

// fallback pool (fp32 h input)
__global__ void pool_kernel(const float* __restrict__ h, const int* __restrict__ batch,
                            const float* __restrict__ wsw, const float* __restrict__ wsb,
                            float* __restrict__ emb) {
    int i = blockIdx.x;
    int t = threadIdx.x;
    float v = fmaxf(h[(size_t)i * HDIM + t], 0.f);
    float p = v * wsw[t];
    for (int off = 32; off >= 1; off >>= 1) p += __shfl_down(p, off, 64);
    __shared__ float red[4];
    __shared__ float ssig;
    if ((t & 63) == 0) red[t >> 6] = p;
    __syncthreads();
    if (t == 0) {
        float s = red[0] + red[1] + red[2] + red[3] + wsb[0];
        ssig = 1.0f / (1.0f + expf(-s));
    }
    __syncthreads();
    atomicAdd(&emb[(size_t)batch[i] * HDIM + t], ssig * v);
}

__global__ void mlp_kernel(const float* __restrict__ emb,
                           const float* __restrict__ m1w, const float* __restrict__ m1b,
                           const float* __restrict__ m2w, const float* __restrict__ m2b,
                           const float* __restrict__ m3w, const float* __restrict__ m3b,
                           const float* __restrict__ ow,  const float* __restrict__ ob,
                           float* __restrict__ out) {
    int g = blockIdx.x;
    int t = threadIdx.x; // 64 threads = 1 wave
    __shared__ float e[HDIM];
    __shared__ float z1[64], z2[64];
    for (int idx = t; idx < HDIM; idx += 64) e[idx] = emb[(size_t)g * HDIM + idx];
    __syncthreads();
    float a = m1b[t];
    for (int k = 0; k < HDIM; ++k) a += e[k] * m1w[k * 64 + t];
    z1[t] = fmaxf(a, 0.f);
    __syncthreads();
    a = m2b[t];
    for (int k = 0; k < 64; ++k) a += z1[k] * m2w[k * 64 + t];
    z2[t] = fmaxf(a, 0.f);
    __syncthreads();
    a = m3b[t];
    for (int k = 0; k < 64; ++k) a += z2[k] * m3w[k * 64 + t];
    float p = a * ow[t];
    for (int off = 32; off >= 1; off >>= 1) p += __shfl_down(p, off, 64);
    if (t == 0) out[g] = p + ob[0];
}

extern "C" void kernel_launch(void* const* d_in, const int* in_sizes, int n_in,
                              void* d_out, int out_size, void* d_ws, size_t ws_size,
                              hipStream_t stream) {
    const float* x     = (const float*)d_in[0];
    const int*   ei    = (const int*)d_in[1];
    const int*   src   = ei;
    const int*   dst   = ei + E_REAL;
    const int*   et    = (const int*)d_in[2];
    const int*   batch = (const int*)d_in[3];
    const float* W1    = (const float*)d_in[4];
    const float* root1 = (const float*)d_in[5];
    const float* b1    = (const float*)d_in[6];
    const float* W2    = (const float*)d_in[7];
    const float* root2 = (const float*)d_in[8];
    const float* b2    = (const float*)d_in[9];
    const float* wsw   = (const float*)d_in[10];
    const float* wsb   = (const float*)d_in[11];
    const float* m1w   = (const float*)d_in[12];
    const float* m1b   = (const float*)d_in[13];
    const float* m2w   = (const float*)d_in[14];
    const float* m2b   = (const float*)d_in[15];
    const float* m3w   = (const float*)d_in[16];
    const float* m3b   = (const float*)d_in[17];
    const float* ow    = (const float*)d_in[18];
    const float* ob    = (const float*)d_in[19];

    char* ws = (char*)d_ws;
    size_t off = 0;
    auto alloc = [&](size_t bytes) {
        void* p = ws + off;
        off = (off + bytes + 255) & ~(size_t)255;
        return p;
    };
    // common buffers
    int*   cnt       = (int*)alloc((size_t)N_NODES * NREL * 4);     // 13.0 MB
    int*   blockHist = (int*)alloc((size_t)TOT_HIST * 4);
    int*   baseArr   = (int*)alloc((size_t)TOT_HIST * 4);
    int*   perm      = (int*)alloc((size_t)E_REAL * 4);             // 0.8 MB
    int*   relStartA = (int*)alloc(NREL * 4);
    int*   relTotA   = (int*)alloc(NREL * 4);
    int*   pbStartA  = (int*)alloc(NREL * 4);
    int*   relOfBlk  = (int*)alloc(MAX_PB * 4);
    int*   npb       = (int*)alloc(4);
    int*   psumA     = (int*)alloc(64 * 4);
    int*   psumB     = (int*)alloc(64 * 4);
    unsigned short* xb  = (unsigned short*)alloc((size_t)N_NODES * 128 * 2);    // 12.8 MB
    unsigned short* w1b = (unsigned short*)alloc((size_t)NREL * 256 * 128 * 2); // 4.3 MB
    unsigned short* w2b = (unsigned short*)alloc((size_t)NREL * 256 * 256 * 2); // 8.5 MB
    unsigned short* r1b = (unsigned short*)alloc((size_t)256 * 128 * 2);
    unsigned short* r2b = (unsigned short*)alloc((size_t)256 * 256 * 2);
    unsigned short* h1b = (unsigned short*)alloc((size_t)N_NODES * HDIM * 2);   // 25.6 MB
    float* emb = (float*)alloc((size_t)NGRAPH * HDIM * 4);                       // 1.6 MB
    size_t off_common = off;

    // fast-path extras
    unsigned short* hinit = (unsigned short*)alloc((size_t)N_NODES * HDIM * 2); // 25.6 MB
    unsigned short* msg   = (unsigned short*)alloc((size_t)E_REAL * HDIM * 2);  // 102.4 MB
    int* qofp    = (int*)alloc((size_t)E_REAL * 4);
    int* cntD    = (int*)alloc((size_t)N_NODES * 4);
    int* startD  = (int*)alloc((size_t)N_NODES * 4);
    int* cursorD = (int*)alloc((size_t)N_NODES * 4);
    size_t need_fast = off;

    float* hf = nullptr;
    bool fast = (ws_size >= need_fast);
    if (!fast) {
        off = off_common;
        hf = (float*)alloc((size_t)N_NODES * HDIM * 4);  // 51.2 MB
        char* hh = (char*)hf;   // dst structures alias hf (used before hf written)
        qofp    = (int*)hh;                                 hh += (size_t)E_REAL * 4;
        cntD    = (int*)hh;                                 hh += (size_t)N_NODES * 4;
        startD  = (int*)hh;                                 hh += (size_t)N_NODES * 4;
        cursorD = (int*)hh;
        hinit = h1b;  // unused sink
        msg = h1b;    // unused sink
    }

    hipMemsetAsync(cnt, 0, (size_t)N_NODES * NREL * 4, stream);
    hipMemsetAsync(cntD, 0, (size_t)N_NODES * 4, stream);
    hipMemsetAsync(emb, 0, (size_t)NGRAPH * HDIM * 4, stream);

    count_kernel<<<NB_CNT, 256, 0, stream>>>(src, dst, et, cnt, blockHist, cntD);
    scan_part<<<64, 1024, 0, stream>>>(blockHist, psumA, TOT_HIST);
    scan_apply<<<64, 1024, 0, stream>>>(blockHist, psumA, baseArr, nullptr, TOT_HIST);
    meta_kernel<<<1, 1024, 0, stream>>>(baseArr, relStartA, relTotA, pbStartA, relOfBlk, npb);
    scan_part<<<64, 1024, 0, stream>>>(cntD, psumB, N_NODES);
    scan_apply<<<64, 1024, 0, stream>>>(cntD, psumB, startD, cursorD, N_NODES);
    scatter_sorted<<<NB_R, 256, 0, stream>>>(src, dst, et, baseArr, perm, cursorD, qofp);

    cvt_rows<<<(N_NODES * 128 / 8 + 255) / 256, 256, 0, stream>>>(x, xb, N_NODES * 128 / 8, 0);
    cvt_wT<<<(NREL * 256 * 16 + 255) / 256, 256, 0, stream>>>(W1, w1b, NREL, 128, 256);
    cvt_wT<<<(NREL * 256 * 32 + 255) / 256, 256, 0, stream>>>(W2, w2b, NREL, 256, 256);
    cvt_wT<<<(256 * 16 + 255) / 256, 256, 0, stream>>>(root1, r1b, 1, 128, 256);
    cvt_wT<<<(256 * 32 + 255) / 256, 256, 0, stream>>>(root2, r2b, 1, 256, 256);

    const int grid_init = (N_NODES + MB - 1) / MB;  // 782

    if (fast) {
        // layer 1
        mfma_gemm<128, 2><<<grid_init, 256, 0, stream>>>(xb, r1b, w1b, b1, nullptr, hinit,
            nullptr, nullptr, nullptr, nullptr, cnt, nullptr, nullptr, nullptr, nullptr, nullptr, nullptr);
        mfma_gemm<128, 3><<<MAX_PB, 256, 0, stream>>>(xb, w1b, nullptr, nullptr, nullptr, msg,
            perm, src, dst, et, cnt, relOfBlk, pbStartA, relStartA, relTotA, npb, qofp);
        reduce_kernel<<<N_NODES / 4, 256, 0, stream>>>(hinit, msg, startD, cntD, h1b);
        // layer 2 (h2 overwrites h1b after GEMMs consume it)
        mfma_gemm<256, 2><<<grid_init, 256, 0, stream>>>(h1b, r2b, w2b, b2, nullptr, hinit,
            nullptr, nullptr, nullptr, nullptr, cnt, nullptr, nullptr, nullptr, nullptr, nullptr, nullptr);
        mfma_gemm<256, 3><<<MAX_PB, 256, 0, stream>>>(h1b, w2b, nullptr, nullptr, nullptr, msg,
            perm, src, dst, et, cnt, relOfBlk, pbStartA, relStartA, relTotA, npb, qofp);
        reduce_kernel<<<N_NODES / 4, 256, 0, stream>>>(hinit, msg, startD, cntD, h1b);
        pool_graph<<<NGRAPH, 256, 0, stream>>>(h1b, batch, wsw, wsb, emb);
    } else {
        mfma_gemm<128, 0><<<grid_init, 256, 0, stream>>>(xb, r1b, w1b, b1, hf, nullptr,
            nullptr, nullptr, nullptr, nullptr, cnt, nullptr, nullptr, nullptr, nullptr, nullptr, nullptr);
        mfma_gemm<128, 1><<<MAX_PB, 256, 0, stream>>>(xb, w1b, nullptr, nullptr, hf, nullptr,
            perm, src, dst, et, cnt, relOfBlk, pbStartA, relStartA, relTotA, npb, nullptr);
        cvt_rows<<<(N_NODES * HDIM / 8 + 255) / 256, 256, 0, stream>>>(hf, h1b, N_NODES * HDIM / 8, 1);
        mfma_gemm<256, 0><<<grid_init, 256, 0, stream>>>(h1b, r2b, w2b, b2, hf, nullptr,
            nullptr, nullptr, nullptr, nullptr, cnt, nullptr, nullptr, nullptr, nullptr, nullptr, nullptr);
        mfma_gemm<256, 1><<<MAX_PB, 256, 0, stream>>>(h1b, w2b, nullptr, nullptr, hf, nullptr,
            perm, src, dst, et, cnt, relOfBlk, pbStartA, relStartA, relTotA, npb, nullptr);
        pool_kernel<<<N_NODES, 256, 0, stream>>>(hf, batch, wsw, wsb, emb);
    }
    mlp_kernel<<<NGRAPH, 64, 0, stream>>>(emb, m1w, m1b, m2w, m2b, m3w, m3b, ow, ob, (float*)d_out);
}